// Round 12
// baseline (880.941 us; speedup 1.0000x reference)
//
#include <hip/hip_runtime.h>
#include <hip/hip_bf16.h>
#include <hip/hip_cooperative_groups.h>
#include <math.h>

namespace cg = cooperative_groups;

#define EPS 1e-5f

// ---------------------------------------------------------------------------
// conv0-style K=4,S=2,P=1 conv: 2 px/thread, 8 couts/thread, aligned float4
// row loads from global (L2-resident), weights in LDS. (L1, L2)
// ---------------------------------------------------------------------------
template<int CIN, int COUT, int H, int W, int TPB>
__global__ __launch_bounds__(TPB) void conv42V(const float* __restrict__ in,
                                               const float* __restrict__ w,
                                               const float* __restrict__ bias,
                                               float* __restrict__ out, int relu)
{
    constexpr int OH  = H / 2, OW = W / 2;
    constexpr int NPX = OH * OW;
    constexpr int PXB = (NPX / 2) / TPB;
    constexpr int NCG = COUT / 8;

    __shared__ float sW[CIN * 8 * 16];   // [ci][co][16]
    __shared__ float sB[8];

    int t   = threadIdx.x;
    int bx  = blockIdx.x;
    int pxb = bx % PXB;
    int cg  = (bx / PXB) % NCG;
    int n   = bx / (PXB * NCG);

    for (int i = t; i < CIN * 128; i += TPB) {
        int ci = i >> 7;
        int r  = i & 127;
        int co = r >> 4;
        int k  = r & 15;
        sW[i] = w[((size_t)(cg * 8 + co) * CIN + ci) * 16 + k];
    }
    if (t < 8) sB[t] = bias[cg * 8 + t];
    __syncthreads();

    int px0 = (pxb * TPB + t) * 2;
    int oh  = px0 / OW;
    int ow0 = px0 % OW;            // even
    int ih0 = oh * 2 - 1;
    int iwq = ow0 * 2;             // multiple of 4

    float acc[8][2];
#pragma unroll
    for (int j = 0; j < 8; ++j) { acc[j][0] = sB[j]; acc[j][1] = sB[j]; }

    const float* ib = in + (size_t)n * CIN * H * W;
#pragma unroll 1
    for (int ci = 0; ci < CIN; ++ci) {
        const float* plane = ib + (size_t)ci * H * W;
#pragma unroll
        for (int kh = 0; kh < 4; ++kh) {
            int ih = ih0 + kh;
            float p[6];
            if ((unsigned)ih < (unsigned)H) {
                const float* row = plane + (size_t)ih * W;
                float4 q = *(const float4*)(row + iwq);
                p[1] = q.x; p[2] = q.y; p[3] = q.z; p[4] = q.w;
                p[0] = (iwq >= 1)     ? row[iwq - 1] : 0.f;
                p[5] = (iwq + 4 < W)  ? row[iwq + 4] : 0.f;
            } else {
#pragma unroll
                for (int k2 = 0; k2 < 6; ++k2) p[k2] = 0.f;
            }
#pragma unroll
            for (int j = 0; j < 8; ++j) {
                const float4 wv = *(const float4*)(sW + (ci * 8 + j) * 16 + kh * 4);
                acc[j][0] = fmaf(p[0], wv.x, acc[j][0]);
                acc[j][0] = fmaf(p[1], wv.y, acc[j][0]);
                acc[j][0] = fmaf(p[2], wv.z, acc[j][0]);
                acc[j][0] = fmaf(p[3], wv.w, acc[j][0]);
                acc[j][1] = fmaf(p[2], wv.x, acc[j][1]);
                acc[j][1] = fmaf(p[3], wv.y, acc[j][1]);
                acc[j][1] = fmaf(p[4], wv.z, acc[j][1]);
                acc[j][1] = fmaf(p[5], wv.w, acc[j][1]);
            }
        }
    }
    float* ob = out + ((size_t)(n * COUT + cg * 8) * NPX) + px0;
#pragma unroll
    for (int j = 0; j < 8; ++j) {
        float2 v;
        v.x = acc[j][0];
        v.y = acc[j][1];
        if (relu) { v.x = fmaxf(v.x, 0.f); v.y = fmaxf(v.y, 0.f); }
        *(float2*)(ob + (size_t)j * NPX) = v;
    }
}

// ---------------------------------------------------------------------------
// L0: (5,256,192)->(8,128,96), +bias +ReLU. grid 1536, block 256.
// ci loop MUST stay unroll 1 (R6: full unroll -> VGPR 256 spill).
// ---------------------------------------------------------------------------
__global__ __launch_bounds__(256) void conv0(const float* __restrict__ in,
                                             const float* __restrict__ w,
                                             const float* __restrict__ bias,
                                             float* __restrict__ out)
{
    __shared__ float sW[5 * 8 * 16];
    __shared__ float sB[8];
    int t   = threadIdx.x;
    int n   = blockIdx.x / 24;
    int pxb = blockIdx.x % 24;
    for (int i = t; i < 640; i += 256) {
        int ci = i / 128;
        int r  = i % 128;
        int co = r / 16;
        int k  = r % 16;
        sW[i] = w[((size_t)co * 5 + ci) * 16 + k];
    }
    if (t < 8) sB[t] = bias[t];
    __syncthreads();

    int px0 = (pxb * 256 + t) * 2;
    int oh  = px0 / 96;
    int ow0 = px0 % 96;
    int ih0 = oh * 2 - 1;
    int iwq = ow0 * 2;

    float acc[8][2];
#pragma unroll
    for (int j = 0; j < 8; ++j) { acc[j][0] = sB[j]; acc[j][1] = sB[j]; }

    const float* ib = in + (size_t)n * 5 * 256 * 192;
#pragma unroll 1
    for (int ci = 0; ci < 5; ++ci) {
        const float* plane = ib + (size_t)ci * 256 * 192;
#pragma unroll
        for (int kh = 0; kh < 4; ++kh) {
            int ih = ih0 + kh;
            float p[6];
            if ((unsigned)ih < 256u) {
                const float* row = plane + (size_t)ih * 192;
                float4 q = *(const float4*)(row + iwq);
                p[1] = q.x; p[2] = q.y; p[3] = q.z; p[4] = q.w;
                p[0] = (iwq >= 1)      ? row[iwq - 1] : 0.f;
                p[5] = (iwq + 4 < 192) ? row[iwq + 4] : 0.f;
            } else {
#pragma unroll
                for (int k2 = 0; k2 < 6; ++k2) p[k2] = 0.f;
            }
#pragma unroll
            for (int j = 0; j < 8; ++j) {
                const float4 wv = *(const float4*)(sW + (ci * 8 + j) * 16 + kh * 4);
                acc[j][0] = fmaf(p[0], wv.x, acc[j][0]);
                acc[j][0] = fmaf(p[1], wv.y, acc[j][0]);
                acc[j][0] = fmaf(p[2], wv.z, acc[j][0]);
                acc[j][0] = fmaf(p[3], wv.w, acc[j][0]);
                acc[j][1] = fmaf(p[2], wv.x, acc[j][1]);
                acc[j][1] = fmaf(p[3], wv.y, acc[j][1]);
                acc[j][1] = fmaf(p[4], wv.z, acc[j][1]);
                acc[j][1] = fmaf(p[5], wv.w, acc[j][1]);
            }
        }
    }
    float* ob = out + (size_t)n * 8 * 12288 + px0;
#pragma unroll
    for (int j = 0; j < 8; ++j) {
        float2 v;
        v.x = fmaxf(acc[j][0], 0.f);
        v.y = fmaxf(acc[j][1], 0.f);
        *(float2*)(ob + (size_t)j * 12288) = v;
    }
}

// ---------------------------------------------------------------------------
// Instance norm for L2 output, writes TRANSPOSED [c][px][n] + relu.
// ---------------------------------------------------------------------------
__global__ __launch_bounds__(256) void inorm_wave_T768(const float* __restrict__ src,
                                                       float* __restrict__ dst_t)
{
    int gid  = blockIdx.x * blockDim.x + threadIdx.x;
    int wv   = gid >> 6;
    int lane = gid & 63;
    int n = wv >> 5;
    int c = wv & 31;
    const float* p = src + (size_t)wv * 768;
    float tv[12];
    float s1 = 0.f, s2 = 0.f;
#pragma unroll
    for (int k = 0; k < 12; ++k) {
        float v = p[lane + k * 64];
        tv[k] = v;
        s1 += v; s2 += v * v;
    }
    for (int m = 32; m >= 1; m >>= 1) {
        s1 += __shfl_xor(s1, m);
        s2 += __shfl_xor(s2, m);
    }
    float mean = s1 * (1.f / 768.f);
    float var  = s2 * (1.f / 768.f) - mean * mean;
    float r = rsqrtf(var + EPS);
#pragma unroll
    for (int k = 0; k < 12; ++k) {
        int i = lane + k * 64;
        float y = fmaxf((tv[k] - mean) * r, 0.f);
        dst_t[((size_t)c * 768 + i) * 64 + n] = y;
    }
}

// ---------------------------------------------------------------------------
// Single-pass instance norm: register-cached float4. HW = TPB*VPT*4. In place.
// ---------------------------------------------------------------------------
template<int TPB, int VPT>
__global__ void inorm_blockv(float* __restrict__ data, int relu)
{
    const int HW = TPB * VPT * 4;
    float4* p = (float4*)(data + (size_t)blockIdx.x * HW);
    float4 v[VPT];
    float s = 0.f, q = 0.f;
#pragma unroll
    for (int k = 0; k < VPT; ++k) {
        v[k] = p[threadIdx.x + k * TPB];
        s += v[k].x + v[k].y + v[k].z + v[k].w;
        q += v[k].x*v[k].x + v[k].y*v[k].y + v[k].z*v[k].z + v[k].w*v[k].w;
    }
    for (int m2 = 32; m2 >= 1; m2 >>= 1) {
        s += __shfl_xor(s, m2);
        q += __shfl_xor(q, m2);
    }
    __shared__ float ss[TPB / 64], sq[TPB / 64], sm[2];
    int wave = threadIdx.x >> 6, lane = threadIdx.x & 63;
    if (lane == 0) { ss[wave] = s; sq[wave] = q; }
    __syncthreads();
    if (threadIdx.x == 0) {
        float a = 0.f, b2 = 0.f;
#pragma unroll
        for (int k = 0; k < TPB / 64; ++k) { a += ss[k]; b2 += sq[k]; }
        float mm = a / (float)HW;
        float vv = b2 / (float)HW - mm * mm;
        sm[0] = mm; sm[1] = rsqrtf(vv + EPS);
    }
    __syncthreads();
    float m = sm[0], r = sm[1];
#pragma unroll
    for (int k = 0; k < VPT; ++k) {
        float4 y;
        y.x = (v[k].x - m) * r; y.y = (v[k].y - m) * r;
        y.z = (v[k].z - m) * r; y.w = (v[k].w - m) * r;
        if (relu) {
            y.x = fmaxf(y.x, 0.f); y.y = fmaxf(y.y, 0.f);
            y.z = fmaxf(y.z, 0.f); y.w = fmaxf(y.w, 0.f);
        }
        p[threadIdx.x + k * TPB] = y;
    }
}

// ===========================================================================
// Shared device stage bodies (used by both coop kernel and fallback kernels)
// ===========================================================================

__device__ __forceinline__ void l3conv_body(const float* __restrict__ At2,
                                            const float* __restrict__ w3,
                                            float* __restrict__ pbuf,
                                            int wid, int lane)
{
    int cog = wid & 31;
    int cic = (wid >> 5) & 3;
    int oh  = wid >> 7;
    int cc  = cic * 8;
    int co0 = cog * 2;
    int ih0 = 2 * oh - 1;

    float acc[2][12];
#pragma unroll
    for (int j = 0; j < 2; ++j)
#pragma unroll
        for (int p = 0; p < 12; ++p) acc[j][p] = 0.f;

    const float* wb = w3 + ((size_t)co0 * 32 + cc) * 16;

#pragma unroll 1
    for (int ci = 0; ci < 8; ++ci) {
        const float* pl = At2 + (size_t)(cc + ci) * 768 * 64 + lane;
        float wr[2][16];
#pragma unroll
        for (int k = 0; k < 16; ++k) {
            wr[0][k] = wb[(0 * 32 + ci) * 16 + k];
            wr[1][k] = wb[(1 * 32 + ci) * 16 + k];
        }
#pragma unroll
        for (int kh = 0; kh < 4; ++kh) {
            int ih = ih0 + kh;
            float p[26];
            p[0] = 0.f; p[25] = 0.f;
            if ((unsigned)ih < 32u) {
#pragma unroll
                for (int c = 0; c < 24; ++c)
                    p[c + 1] = pl[(size_t)(ih * 24 + c) * 64];
            } else {
#pragma unroll
                for (int c = 0; c < 24; ++c) p[c + 1] = 0.f;
            }
#pragma unroll
            for (int ow = 0; ow < 12; ++ow) {
#pragma unroll
                for (int kw = 0; kw < 4; ++kw) {
                    float pv = p[2 * ow + kw];
                    acc[0][ow] = fmaf(pv, wr[0][kh * 4 + kw], acc[0][ow]);
                    acc[1][ow] = fmaf(pv, wr[1][kh * 4 + kw], acc[1][ow]);
                }
            }
        }
    }
    float* pb = pbuf + ((size_t)cic * 4096 + (size_t)lane * 64 + co0) * 192 + oh * 12;
#pragma unroll
    for (int j = 0; j < 2; ++j) {
        float4* o4 = (float4*)(pb + (size_t)j * 192);
        o4[0] = make_float4(acc[j][0], acc[j][1], acc[j][2],  acc[j][3]);
        o4[1] = make_float4(acc[j][4], acc[j][5], acc[j][6],  acc[j][7]);
        o4[2] = make_float4(acc[j][8], acc[j][9], acc[j][10], acc[j][11]);
    }
}

__device__ __forceinline__ void l3red_body(const float* __restrict__ pbuf,
                                           float* __restrict__ At,
                                           int wv, int lane)
{
    int n  = wv >> 6;
    int co = wv & 63;
    float tv[3];
#pragma unroll
    for (int k = 0; k < 3; ++k) {
        int i = lane + k * 64;
        float sum = 0.f;
#pragma unroll
        for (int s = 0; s < 4; ++s)
            sum += pbuf[((size_t)s * 4096 + wv) * 192 + i];
        tv[k] = sum;
    }
    float s1 = tv[0] + tv[1] + tv[2];
    float s2 = tv[0]*tv[0] + tv[1]*tv[1] + tv[2]*tv[2];
    for (int m = 32; m >= 1; m >>= 1) {
        s1 += __shfl_xor(s1, m);
        s2 += __shfl_xor(s2, m);
    }
    float mean = s1 * (1.f / 192.f);
    float var  = s2 * (1.f / 192.f) - mean * mean;
    float r = rsqrtf(var + EPS);
#pragma unroll
    for (int k = 0; k < 3; ++k) {
        int i = lane + k * 64;
        float y = fmaxf((tv[k] - mean) * r, 0.f);
        At[((size_t)co * 192 + i) * 64 + n] = y;
    }
}

__device__ __forceinline__ void l4conv_body(const float* __restrict__ At,
                                            const float* __restrict__ w4,
                                            float* __restrict__ pbuf,
                                            int wid, int lane)
{
    int cog  = wid & 63;
    int cic  = (wid >> 6) & 7;
    int half = wid >> 9;
    int cc   = cic * 8;
    int co0  = cog * 2;
    int oh0  = half * 4;

    float acc[2][24];
#pragma unroll
    for (int j = 0; j < 2; ++j)
#pragma unroll
        for (int p = 0; p < 24; ++p) acc[j][p] = 0.f;

    const float* wp = w4 + ((size_t)co0 * 64 + cc) * 16;

#pragma unroll 1
    for (int ci = 0; ci < 8; ++ci) {
        const float* pl = At + (size_t)(cc + ci) * 192 * 64 + lane;
        float wr[2][16];
#pragma unroll
        for (int k = 0; k < 16; ++k) {
            wr[0][k] = wp[(0 * 64 + ci) * 16 + k];
            wr[1][k] = wp[(1 * 64 + ci) * 16 + k];
        }
#pragma unroll
        for (int kh = 0; kh < 4; ++kh) {
            float p[4][12];
#pragma unroll
            for (int o = 0; o < 4; ++o) {
                int ih = 2 * (oh0 + o) - 1 + kh;
                if ((unsigned)ih < 16u) {
#pragma unroll
                    for (int c = 0; c < 12; ++c)
                        p[o][c] = pl[(size_t)(ih * 12 + c) * 64];
                } else {
#pragma unroll
                    for (int c = 0; c < 12; ++c) p[o][c] = 0.f;
                }
            }
#pragma unroll
            for (int o = 0; o < 4; ++o)
#pragma unroll
                for (int ow = 0; ow < 6; ++ow) {
#pragma unroll
                    for (int kw = 0; kw < 4; ++kw) {
                        int iw = 2 * ow - 1 + kw;
                        if (iw < 0 || iw >= 12) continue;
                        float pv = p[o][iw];
                        acc[0][o * 6 + ow] = fmaf(pv, wr[0][kh * 4 + kw], acc[0][o * 6 + ow]);
                        acc[1][o * 6 + ow] = fmaf(pv, wr[1][kh * 4 + kw], acc[1][o * 6 + ow]);
                    }
                }
        }
    }
    float* pb = pbuf + ((size_t)(cic * 64 + lane) * 128 + co0) * 48 + oh0 * 6;
#pragma unroll
    for (int j = 0; j < 2; ++j) {
        float4* o4 = (float4*)(pb + j * 48);
#pragma unroll
        for (int q = 0; q < 6; ++q)
            o4[q] = make_float4(acc[j][q * 4 + 0], acc[j][q * 4 + 1],
                                acc[j][q * 4 + 2], acc[j][q * 4 + 3]);
    }
}

__device__ __forceinline__ void red48_body(const float* __restrict__ pbuf,
                                           float* __restrict__ outp, int g)
{
    int co = g & 127;
    int n  = g >> 7;
    float s[48];
#pragma unroll
    for (int p = 0; p < 48; ++p) s[p] = 0.f;
#pragma unroll 1
    for (int c = 0; c < 8; ++c) {
        const float4* p4 = (const float4*)(pbuf + ((size_t)(c * 64 + n) * 128 + co) * 48);
#pragma unroll
        for (int q = 0; q < 12; ++q) {
            float4 a = p4[q];
            s[q * 4 + 0] += a.x; s[q * 4 + 1] += a.y;
            s[q * 4 + 2] += a.z; s[q * 4 + 3] += a.w;
        }
    }
    float m = 0.f;
#pragma unroll
    for (int p = 0; p < 48; ++p) m += s[p];
    m *= (1.f / 48.f);
    float q = 0.f;
#pragma unroll
    for (int p = 0; p < 48; ++p) { float d = s[p] - m; q += d * d; }
    q *= (1.f / 48.f);
    float r = rsqrtf(q + EPS);
    float4* o4 = (float4*)(outp + ((size_t)n * 128 + co) * 48);
#pragma unroll
    for (int qq = 0; qq < 12; ++qq) {
        float4 v;
        v.x = fmaxf((s[qq * 4 + 0] - m) * r, 0.f);
        v.y = fmaxf((s[qq * 4 + 1] - m) * r, 0.f);
        v.z = fmaxf((s[qq * 4 + 2] - m) * r, 0.f);
        v.w = fmaxf((s[qq * 4 + 3] - m) * r, 0.f);
        o4[qq] = v;
    }
}

__device__ __forceinline__ void l5conv_body(const float* __restrict__ l4out,
                                            const float* __restrict__ w5,
                                            float* __restrict__ pbuf,
                                            int wid, int lane)
{
    int cic = wid >> 6;
    int cog = wid & 63;
    int cc  = cic * 8;
    int co0 = cog * 4;

    float acc[4][12];
#pragma unroll
    for (int j = 0; j < 4; ++j)
#pragma unroll
        for (int p = 0; p < 12; ++p) acc[j][p] = 0.f;

    const float* ip = l4out + ((size_t)lane * 128 + cc) * 48;
    const float* wp = w5 + ((size_t)co0 * 128 + cc) * 16;

#pragma unroll 1
    for (int ci = 0; ci < 8; ++ci) {
        float p[48];
        const float4* p4 = (const float4*)(ip + ci * 48);
#pragma unroll
        for (int q = 0; q < 12; ++q) {
            float4 a = p4[q];
            p[q * 4 + 0] = a.x; p[q * 4 + 1] = a.y;
            p[q * 4 + 2] = a.z; p[q * 4 + 3] = a.w;
        }
#pragma unroll
        for (int j = 0; j < 4; ++j) {
            const float* wj = wp + ((size_t)j * 128 + ci) * 16;
            float wr[16];
#pragma unroll
            for (int k = 0; k < 16; ++k) wr[k] = wj[k];
#pragma unroll
            for (int oh = 0; oh < 4; ++oh)
#pragma unroll
                for (int ow = 0; ow < 3; ++ow) {
                    int ih0 = 2 * oh - 1, iw0 = 2 * ow - 1;
#pragma unroll
                    for (int kh = 0; kh < 4; ++kh) {
                        int ih = ih0 + kh;
                        if (ih < 0 || ih >= 8) continue;
#pragma unroll
                        for (int kw = 0; kw < 4; ++kw) {
                            int iw = iw0 + kw;
                            if (iw < 0 || iw >= 6) continue;
                            acc[j][oh * 3 + ow] =
                                fmaf(p[ih * 6 + iw], wr[kh * 4 + kw], acc[j][oh * 3 + ow]);
                        }
                    }
                }
        }
    }
    float* pb = pbuf + ((size_t)(cic * 64 + lane) * 256 + co0) * 12;
#pragma unroll
    for (int j = 0; j < 4; ++j) {
        float4* o4 = (float4*)(pb + j * 12);
        o4[0] = make_float4(acc[j][0], acc[j][1], acc[j][2],  acc[j][3]);
        o4[1] = make_float4(acc[j][4], acc[j][5], acc[j][6],  acc[j][7]);
        o4[2] = make_float4(acc[j][8], acc[j][9], acc[j][10], acc[j][11]);
    }
}

__device__ __forceinline__ void red12_body(const float* __restrict__ pbuf,
                                           float* __restrict__ outp, int g)
{
    int co = g & 255;
    int n  = g >> 8;
    float s[12];
#pragma unroll
    for (int p = 0; p < 12; ++p) s[p] = 0.f;
#pragma unroll 1
    for (int c = 0; c < 16; ++c) {
        const float4* p4 = (const float4*)(pbuf + ((size_t)(c * 64 + n) * 256 + co) * 12);
        float4 a = p4[0], b = p4[1], d = p4[2];
        s[0] += a.x; s[1] += a.y; s[2]  += a.z; s[3]  += a.w;
        s[4] += b.x; s[5] += b.y; s[6]  += b.z; s[7]  += b.w;
        s[8] += d.x; s[9] += d.y; s[10] += d.z; s[11] += d.w;
    }
    float m = 0.f;
#pragma unroll
    for (int p = 0; p < 12; ++p) m += s[p];
    m *= (1.f / 12.f);
    float q = 0.f;
#pragma unroll
    for (int p = 0; p < 12; ++p) { float d = s[p] - m; q += d * d; }
    q *= (1.f / 12.f);
    float r = rsqrtf(q + EPS);
    float4* o4 = (float4*)(outp + ((size_t)n * 256 + co) * 12);
    float y[12];
#pragma unroll
    for (int p = 0; p < 12; ++p) y[p] = fmaxf((s[p] - m) * r, 0.f);
    o4[0] = make_float4(y[0], y[1], y[2],  y[3]);
    o4[1] = make_float4(y[4], y[5], y[6],  y[7]);
    o4[2] = make_float4(y[8], y[9], y[10], y[11]);
}

__device__ __forceinline__ void conv67_body(const float* __restrict__ in,
                                            const float* __restrict__ w,
                                            float* __restrict__ pbuf,
                                            int gw, int lane)
{
    int cic = gw >> 6;
    int cog = gw & 63;
    int cc  = cic * 16;
    int co0 = cog * 4;

    float acc[4][12];
#pragma unroll
    for (int j = 0; j < 4; ++j)
#pragma unroll
        for (int p = 0; p < 12; ++p) acc[j][p] = 0.f;

    const float* ip = in + ((size_t)lane * 256 + cc) * 12;
    const float* wp = w + ((size_t)co0 * 256 + cc) * 9;

#pragma unroll 2
    for (int ci = 0; ci < 16; ++ci) {
        float p[12];
        const float4* p4 = (const float4*)(ip + ci * 12);
        float4 a0 = p4[0], a1 = p4[1], a2 = p4[2];
        p[0] = a0.x; p[1] = a0.y; p[2]  = a0.z; p[3]  = a0.w;
        p[4] = a1.x; p[5] = a1.y; p[6]  = a1.z; p[7]  = a1.w;
        p[8] = a2.x; p[9] = a2.y; p[10] = a2.z; p[11] = a2.w;
#pragma unroll
        for (int j = 0; j < 4; ++j) {
            const float* wj = wp + ((size_t)j * 256 + ci) * 9;
            float wr[9];
#pragma unroll
            for (int k = 0; k < 9; ++k) wr[k] = wj[k];
#pragma unroll
            for (int oh = 0; oh < 4; ++oh)
#pragma unroll
                for (int ow = 0; ow < 3; ++ow)
#pragma unroll
                    for (int kh = 0; kh < 3; ++kh) {
                        int ih = oh - 1 + kh;
                        if (ih < 0 || ih >= 4) continue;
#pragma unroll
                        for (int kw = 0; kw < 3; ++kw) {
                            int iw = ow - 1 + kw;
                            if (iw < 0 || iw >= 3) continue;
                            acc[j][oh * 3 + ow] =
                                fmaf(p[ih * 3 + iw], wr[kh * 3 + kw], acc[j][oh * 3 + ow]);
                        }
                    }
        }
    }
    float* pb = pbuf + ((size_t)(cic * 64 + lane) * 256 + co0) * 12;
#pragma unroll
    for (int j = 0; j < 4; ++j) {
        float4* o4 = (float4*)(pb + j * 12);
        o4[0] = make_float4(acc[j][0], acc[j][1], acc[j][2],  acc[j][3]);
        o4[1] = make_float4(acc[j][4], acc[j][5], acc[j][6],  acc[j][7]);
        o4[2] = make_float4(acc[j][8], acc[j][9], acc[j][10], acc[j][11]);
    }
}

// ===========================================================================
// Cooperative mega-kernel: 256 blocks x 256 thr (1 block/CU guaranteed
// co-resident at any VGPR). Stages needing more waves loop internally.
// ===========================================================================
__global__ __launch_bounds__(256) void coop_tail(const float* __restrict__ w3,
                                                 const float* __restrict__ w4,
                                                 const float* __restrict__ w5,
                                                 const float* __restrict__ w6,
                                                 const float* __restrict__ w7,
                                                 const float* __restrict__ fc1_w,
                                                 const float* __restrict__ fc1_b,
                                                 const float* __restrict__ fc2_w,
                                                 const float* __restrict__ fc2_b,
                                                 float* __restrict__ out,
                                                 float* __restrict__ ws)
{
    cg::grid_group grid = cg::this_grid();
    __shared__ float smem[3520];

    float* At    = ws;
    float* At2   = ws + 1572864;
    float* l4out = ws + 1048576;
    float* pbuf  = ws + 3145728;
    float* Bf    = ws + 6291456;
    float* l7out = Bf + 262144;
    float* fc1o  = ws + 9469952;

    int t      = threadIdx.x;
    int lane   = t & 63;
    int waveId = __builtin_amdgcn_readfirstlane(blockIdx.x * 4 + (t >> 6)); // 0..1023
    int g      = blockIdx.x * 256 + t;                                     // 0..65535

    // L3 conv: 2048 units
#pragma unroll 1
    for (int u = 0; u < 2; ++u) l3conv_body(At2, w3, pbuf, waveId + u * 1024, lane);
    grid.sync();

    // L3 reduce: 4096 units
#pragma unroll 1
    for (int u = 0; u < 4; ++u) l3red_body(pbuf, At, waveId + u * 1024, lane);
    grid.sync();

    l4conv_body(At, w4, pbuf, waveId, lane);       // 1024 units
    grid.sync();
    if (g < 8192) red48_body(pbuf, l4out, g);
    grid.sync();

    l5conv_body(l4out, w5, pbuf, waveId, lane);    // 1024 units
    grid.sync();
    if (g < 16384) red12_body(pbuf, Bf, g);
    grid.sync();

    conv67_body(Bf, w6, pbuf, waveId, lane);       // 1024 units
    grid.sync();
    if (g < 16384) red12_body(pbuf, At, g);
    grid.sync();

    conv67_body(At, w7, pbuf, waveId, lane);
    grid.sync();
    if (g < 16384) red12_body(pbuf, l7out, g);
    grid.sync();

    // pool + fc1 (blocks 0..31, 2 n per block)
    if (blockIdx.x < 32) {
        int half = t >> 7;
        int tl   = t & 127;
        int n    = blockIdx.x * 2 + half;
        float* sPool = smem + half * 512;
        for (int f = tl; f < 512; f += 128) {
            int c = f >> 1;
            int h = f & 1;
            const float* p = l7out + (((size_t)n * 256 + c) * 4 + h * 2) * 3;
            sPool[f] = fmaxf(fmaxf(p[0], p[1]), fmaxf(p[3], p[4]));
        }
        __syncthreads();
        int j = tl;
        const float* wr = fc1_w + j * 512;
        float acc = fc1_b[j];
#pragma unroll 4
        for (int f = 0; f < 512; ++f) acc = fmaf(sPool[f], wr[f], acc);
        fc1o[n * 128 + j] = fmaxf(acc, 0.f);
    }
    grid.sync();

    // fc2 + tanh + losses (block 0)
    if (blockIdx.x == 0) {
        float* sPts = smem;
        float* sAcc = smem + 3200;
        for (int idx = t; idx < 3200; idx += 256) {
            int n = idx / 50;
            int k = idx % 50;
            const float* xv = fc1o + n * 128;
            const float* wr = fc2_w + k * 128;
            float acc = fc2_b[k];
#pragma unroll 4
            for (int f = 0; f < 128; ++f) acc = fmaf(xv[f], wr[f], acc);
            float v = tanhf(acc);
            out[idx]  = v;
            sPts[idx] = v;
        }
        __syncthreads();
        if (t < 64) {
            int n = t;
            float rx = 0.f, ry = 0.f, cx = 0.f, cy = 0.f;
            const float* gp = sPts + n * 50;
            for (int r = 0; r < 5; ++r)
                for (int j = 0; j < 3; ++j)
                    for (int d = 0; d < 2; ++d) {
                        float a0 = gp[(r * 5 + j) * 2 + d];
                        float a1 = gp[(r * 5 + j + 1) * 2 + d];
                        float a2 = gp[(r * 5 + j + 2) * 2 + d];
                        float d0 = (a1 - a0) * (a1 - a0);
                        float d1 = (a2 - a1) * (a2 - a1);
                        float tt = fmaxf(0.08f, fabsf(d1 - d0));
                        if (d == 0) rx += tt; else ry += tt;
                    }
            for (int r = 0; r < 5; ++r)
                for (int j = 0; j < 3; ++j)
                    for (int d = 0; d < 2; ++d) {
                        float a0 = gp[(j * 5 + r) * 2 + d];
                        float a1 = gp[((j + 1) * 5 + r) * 2 + d];
                        float a2 = gp[((j + 2) * 5 + r) * 2 + d];
                        float d0 = (a1 - a0) * (a1 - a0);
                        float d1 = (a2 - a1) * (a2 - a1);
                        float tt = fmaxf(0.08f, fabsf(d1 - d0));
                        if (d == 0) cx += tt; else cy += tt;
                    }
            sAcc[0 * 64 + n] = rx; sAcc[1 * 64 + n] = ry;
            sAcc[2 * 64 + n] = cx; sAcc[3 * 64 + n] = cy;
        }
        __syncthreads();
        if (t == 0) {
            float s0 = 0.f, s1 = 0.f, s2 = 0.f, s3 = 0.f;
            for (int i = 0; i < 64; ++i) {
                s0 += sAcc[0 * 64 + i]; s1 += sAcc[1 * 64 + i];
                s2 += sAcc[2 * 64 + i]; s3 += sAcc[3 * 64 + i];
            }
            float inv = 1.0f / (64.0f * 15.0f);
            out[3200] = s0 * inv;
            out[3201] = s1 * inv;
            out[3202] = s2 * inv;
            out[3203] = s3 * inv;
            const float* gp = sPts;
            float rg = 0.f, cgs = 0.f;
            for (int r = 0; r < 5; ++r)
                for (int j = 0; j < 3; ++j) {
                    float x0 = gp[(r * 5 + j) * 2],     y0 = gp[(r * 5 + j) * 2 + 1];
                    float x1 = gp[(r * 5 + j + 1) * 2], y1 = gp[(r * 5 + j + 1) * 2 + 1];
                    float x2 = gp[(r * 5 + j + 2) * 2], y2 = gp[(r * 5 + j + 2) * 2 + 1];
                    rg += fabsf((y1 - y0) * (x1 - x2) - (y1 - y2) * (x1 - x0));
                }
            for (int r = 0; r < 5; ++r)
                for (int j = 0; j < 3; ++j) {
                    float x0 = gp[(j * 5 + r) * 2],       y0 = gp[(j * 5 + r) * 2 + 1];
                    float x1 = gp[((j + 1) * 5 + r) * 2], y1 = gp[((j + 1) * 5 + r) * 2 + 1];
                    float x2 = gp[((j + 2) * 5 + r) * 2], y2 = gp[((j + 2) * 5 + r) * 2 + 1];
                    cgs += fabsf((y1 - y0) * (x1 - x2) - (y1 - y2) * (x1 - x0));
                }
            out[3204] = fmaxf(rg, 0.02f);
            out[3205] = fmaxf(cgs, 0.02f);
        }
    }
}

// ===========================================================================
// Fallback discrete kernels (R10 path), built on the shared bodies
// ===========================================================================
__global__ __launch_bounds__(256) void k_l3conv(const float* At2, const float* w3, float* pbuf)
{
    int t = threadIdx.x;
    l3conv_body(At2, w3, pbuf,
                __builtin_amdgcn_readfirstlane(blockIdx.x * 4 + (t >> 6)), t & 63);
}
__global__ __launch_bounds__(256) void k_l3red(const float* pbuf, float* At)
{
    int t = threadIdx.x;
    l3red_body(pbuf, At,
               __builtin_amdgcn_readfirstlane(blockIdx.x * 4 + (t >> 6)), t & 63);
}
__global__ __launch_bounds__(256) void k_l4conv(const float* At, const float* w4, float* pbuf)
{
    int t = threadIdx.x;
    l4conv_body(At, w4, pbuf,
                __builtin_amdgcn_readfirstlane(blockIdx.x * 4 + (t >> 6)), t & 63);
}
__global__ __launch_bounds__(256) void k_red48(const float* pbuf, float* outp)
{
    red48_body(pbuf, outp, blockIdx.x * 256 + threadIdx.x);
}
__global__ __launch_bounds__(256) void k_l5conv(const float* in, const float* w5, float* pbuf)
{
    int t = threadIdx.x;
    l5conv_body(in, w5, pbuf,
                __builtin_amdgcn_readfirstlane(blockIdx.x * 4 + (t >> 6)), t & 63);
}
__global__ __launch_bounds__(256) void k_red12(const float* pbuf, float* outp)
{
    red12_body(pbuf, outp, blockIdx.x * 256 + threadIdx.x);
}
__global__ __launch_bounds__(256) void k_conv67(const float* in, const float* w, float* pbuf)
{
    int t = threadIdx.x;
    conv67_body(in, w, pbuf,
                __builtin_amdgcn_readfirstlane(blockIdx.x * 4 + (t >> 6)), t & 63);
}
__global__ void pool_kernel(const float* __restrict__ in, float* __restrict__ out)
{
    int idx = blockIdx.x * blockDim.x + threadIdx.x;
    if (idx >= 64 * 512) return;
    int f = idx & 511;
    int n = idx >> 9;
    int c = f >> 1;
    int h = f & 1;
    const float* p = in + (((size_t)n * 256 + c) * 4 + h * 2) * 3;
    out[idx] = fmaxf(fmaxf(p[0], p[1]), fmaxf(p[3], p[4]));
}
__global__ void fc1_kernel(const float* __restrict__ in, const float* __restrict__ w,
                           const float* __restrict__ b, float* __restrict__ out)
{
    int idx = blockIdx.x * blockDim.x + threadIdx.x;
    if (idx >= 64 * 128) return;
    int j = idx & 127;
    int n = idx >> 7;
    const float* x  = in + n * 512;
    const float* wr = w + j * 512;
    float acc = b[j];
    for (int f = 0; f < 512; ++f) acc = fmaf(x[f], wr[f], acc);
    out[idx] = fmaxf(acc, 0.f);
}
__global__ void fc2_kernel(const float* __restrict__ in, const float* __restrict__ w,
                           const float* __restrict__ b, float* __restrict__ out)
{
    int idx = blockIdx.x * blockDim.x + threadIdx.x;
    if (idx >= 64 * 50) return;
    int k = idx % 50;
    int n = idx / 50;
    const float* x  = in + n * 128;
    const float* wr = w + k * 128;
    float acc = b[k];
    for (int f = 0; f < 128; ++f) acc = fmaf(x[f], wr[f], acc);
    out[idx] = tanhf(acc);
}
__global__ void loss_kernel(const float* __restrict__ pts, float* __restrict__ out)
{
    __shared__ float acc[4][64];
    int n = threadIdx.x;
    float rx = 0.f, ry = 0.f, cx = 0.f, cy = 0.f;
    {
        const float* g = pts + n * 50;
        for (int r = 0; r < 5; ++r)
            for (int j = 0; j < 3; ++j)
                for (int d = 0; d < 2; ++d) {
                    float a0 = g[(r * 5 + j) * 2 + d];
                    float a1 = g[(r * 5 + j + 1) * 2 + d];
                    float a2 = g[(r * 5 + j + 2) * 2 + d];
                    float d0 = (a1 - a0) * (a1 - a0);
                    float d1 = (a2 - a1) * (a2 - a1);
                    float t = fmaxf(0.08f, fabsf(d1 - d0));
                    if (d == 0) rx += t; else ry += t;
                }
        for (int r = 0; r < 5; ++r)
            for (int j = 0; j < 3; ++j)
                for (int d = 0; d < 2; ++d) {
                    float a0 = g[(j * 5 + r) * 2 + d];
                    float a1 = g[((j + 1) * 5 + r) * 2 + d];
                    float a2 = g[((j + 2) * 5 + r) * 2 + d];
                    float d0 = (a1 - a0) * (a1 - a0);
                    float d1 = (a2 - a1) * (a2 - a1);
                    float t = fmaxf(0.08f, fabsf(d1 - d0));
                    if (d == 0) cx += t; else cy += t;
                }
    }
    acc[0][n] = rx; acc[1][n] = ry; acc[2][n] = cx; acc[3][n] = cy;
    __syncthreads();
    if (n == 0) {
        float s0 = 0.f, s1 = 0.f, s2 = 0.f, s3 = 0.f;
        for (int i = 0; i < 64; ++i) {
            s0 += acc[0][i]; s1 += acc[1][i]; s2 += acc[2][i]; s3 += acc[3][i];
        }
        float inv = 1.0f / (64.0f * 15.0f);
        out[3200] = s0 * inv;
        out[3201] = s1 * inv;
        out[3202] = s2 * inv;
        out[3203] = s3 * inv;
        const float* g = pts;
        float rg = 0.f, cg = 0.f;
        for (int r = 0; r < 5; ++r)
            for (int j = 0; j < 3; ++j) {
                float x0 = g[(r * 5 + j) * 2],     y0 = g[(r * 5 + j) * 2 + 1];
                float x1 = g[(r * 5 + j + 1) * 2], y1 = g[(r * 5 + j + 1) * 2 + 1];
                float x2 = g[(r * 5 + j + 2) * 2], y2 = g[(r * 5 + j + 2) * 2 + 1];
                rg += fabsf((y1 - y0) * (x1 - x2) - (y1 - y2) * (x1 - x0));
            }
        for (int r = 0; r < 5; ++r)
            for (int j = 0; j < 3; ++j) {
                float x0 = g[(j * 5 + r) * 2],       y0 = g[(j * 5 + r) * 2 + 1];
                float x1 = g[((j + 1) * 5 + r) * 2], y1 = g[((j + 1) * 5 + r) * 2 + 1];
                float x2 = g[((j + 2) * 5 + r) * 2], y2 = g[((j + 2) * 5 + r) * 2 + 1];
                cg += fabsf((y1 - y0) * (x1 - x2) - (y1 - y2) * (x1 - x0));
            }
        out[3204] = fmaxf(rg, 0.02f);
        out[3205] = fmaxf(cg, 0.02f);
    }
}

extern "C" void kernel_launch(void* const* d_in, const int* in_sizes, int n_in,
                              void* d_out, int out_size, void* d_ws, size_t ws_size,
                              hipStream_t stream)
{
    const float* x = (const float*)d_in[0];
    const float* w[8], *bia[8];
    for (int i = 0; i < 6; ++i) { w[i] = (const float*)d_in[1 + 2 * i]; bia[i] = (const float*)d_in[2 + 2 * i]; }
    w[6] = (const float*)d_in[13]; bia[6] = (const float*)d_in[14];
    w[7] = (const float*)d_in[15]; bia[7] = (const float*)d_in[16];
    const float* fc1_w = (const float*)d_in[17];
    const float* fc1_b = (const float*)d_in[18];
    const float* fc2_w = (const float*)d_in[19];
    const float* fc2_b = (const float*)d_in[20];
    float* out = (float*)d_out;

    float* A     = (float*)d_ws;
    float* At    = A;
    float* At2   = A + 1572864;
    float* l4out = A + 1048576;
    float* pbuf  = A + 3145728;
    float* Bf    = A + 6291456;
    float* l7out = Bf + 262144;
    float* fc1o  = A + 9469952;

    const int N = 64;

    // ---- L0 ----
    conv0<<<1536, 256, 0, stream>>>(x, w[0], bia[0], A);
    inorm_blockv<256, 12><<<N * 8, 256, 0, stream>>>(A, 0);

    // ---- L1 ----
    conv42V<8, 16, 128, 96, 256><<<768, 256, 0, stream>>>(A, w[1], bia[1], Bf, 0);
    inorm_blockv<256, 3><<<N * 16, 256, 0, stream>>>(Bf, 1);

    // ---- L2: raw out -> A, norm -> At2 (transposed) ----
    conv42V<16, 32, 64, 48, 192><<<512, 192, 0, stream>>>(Bf, w[2], bia[2], A, 0);
    inorm_wave_T768<<<512, 256, 0, stream>>>(A, At2);

    // ---- L3..losses: cooperative (256 blocks, guaranteed co-resident) ----
    float* ws_f = A;
    void* args[] = {
        (void*)&w[3], (void*)&w[4], (void*)&w[5], (void*)&w[6], (void*)&w[7],
        (void*)&fc1_w, (void*)&fc1_b, (void*)&fc2_w, (void*)&fc2_b,
        (void*)&out, (void*)&ws_f
    };
    hipError_t err = hipLaunchCooperativeKernel((void*)coop_tail, dim3(256), dim3(256),
                                                args, 0, stream);
    if (err != hipSuccess) {
        // Fallback: discrete launches (R10-proven path, same math)
        k_l3conv<<<512, 256, 0, stream>>>(At2, w[3], pbuf);
        k_l3red<<<1024, 256, 0, stream>>>(pbuf, At);
        k_l4conv<<<256, 256, 0, stream>>>(At, w[4], pbuf);
        k_red48<<<32, 256, 0, stream>>>(pbuf, l4out);
        k_l5conv<<<256, 256, 0, stream>>>(l4out, w[5], pbuf);
        k_red12<<<64, 256, 0, stream>>>(pbuf, Bf);
        k_conv67<<<256, 256, 0, stream>>>(Bf, w[6], pbuf);
        k_red12<<<64, 256, 0, stream>>>(pbuf, At);
        k_conv67<<<256, 256, 0, stream>>>(At, w[7], pbuf);
        k_red12<<<64, 256, 0, stream>>>(pbuf, l7out);
        pool_kernel<<<(64 * 512 + 255) / 256, 256, 0, stream>>>(l7out, Bf + 3145728 - 32768);
        float* pooled = Bf + 3145728 - 32768;
        fc1_kernel<<<(64 * 128 + 255) / 256, 256, 0, stream>>>(pooled, fc1_w, fc1_b, fc1o);
        fc2_kernel<<<(64 * 50 + 255) / 256, 256, 0, stream>>>(fc1o, fc2_w, fc2_b, out);
        loss_kernel<<<1, 64, 0, stream>>>(out, out);
    }
}

// Round 13
// 590.966 us; speedup vs baseline: 1.4907x; 1.4907x over previous
//
#include <hip/hip_runtime.h>
#include <hip/hip_bf16.h>
#include <math.h>

#define EPS 1e-5f

// ---------------------------------------------------------------------------
// conv0-style K=4,S=2,P=1 conv: 2 px/thread, 8 couts/thread, aligned float4
// row loads from global (L2-resident), weights in LDS. (L1, L2)
// ---------------------------------------------------------------------------
template<int CIN, int COUT, int H, int W, int TPB>
__global__ __launch_bounds__(TPB) void conv42V(const float* __restrict__ in,
                                               const float* __restrict__ w,
                                               const float* __restrict__ bias,
                                               float* __restrict__ out, int relu)
{
    constexpr int OH  = H / 2, OW = W / 2;
    constexpr int NPX = OH * OW;
    constexpr int PXB = (NPX / 2) / TPB;
    constexpr int NCG = COUT / 8;

    __shared__ float sW[CIN * 8 * 16];   // [ci][co][16]
    __shared__ float sB[8];

    int t   = threadIdx.x;
    int bx  = blockIdx.x;
    int pxb = bx % PXB;
    int cg  = (bx / PXB) % NCG;
    int n   = bx / (PXB * NCG);

    for (int i = t; i < CIN * 128; i += TPB) {
        int ci = i >> 7;
        int r  = i & 127;
        int co = r >> 4;
        int k  = r & 15;
        sW[i] = w[((size_t)(cg * 8 + co) * CIN + ci) * 16 + k];
    }
    if (t < 8) sB[t] = bias[cg * 8 + t];
    __syncthreads();

    int px0 = (pxb * TPB + t) * 2;
    int oh  = px0 / OW;
    int ow0 = px0 % OW;            // even
    int ih0 = oh * 2 - 1;
    int iwq = ow0 * 2;             // multiple of 4

    float acc[8][2];
#pragma unroll
    for (int j = 0; j < 8; ++j) { acc[j][0] = sB[j]; acc[j][1] = sB[j]; }

    const float* ib = in + (size_t)n * CIN * H * W;
#pragma unroll 1
    for (int ci = 0; ci < CIN; ++ci) {
        const float* plane = ib + (size_t)ci * H * W;
#pragma unroll
        for (int kh = 0; kh < 4; ++kh) {
            int ih = ih0 + kh;
            float p[6];
            if ((unsigned)ih < (unsigned)H) {
                const float* row = plane + (size_t)ih * W;
                float4 q = *(const float4*)(row + iwq);
                p[1] = q.x; p[2] = q.y; p[3] = q.z; p[4] = q.w;
                p[0] = (iwq >= 1)     ? row[iwq - 1] : 0.f;
                p[5] = (iwq + 4 < W)  ? row[iwq + 4] : 0.f;
            } else {
#pragma unroll
                for (int k2 = 0; k2 < 6; ++k2) p[k2] = 0.f;
            }
#pragma unroll
            for (int j = 0; j < 8; ++j) {
                const float4 wv = *(const float4*)(sW + (ci * 8 + j) * 16 + kh * 4);
                acc[j][0] = fmaf(p[0], wv.x, acc[j][0]);
                acc[j][0] = fmaf(p[1], wv.y, acc[j][0]);
                acc[j][0] = fmaf(p[2], wv.z, acc[j][0]);
                acc[j][0] = fmaf(p[3], wv.w, acc[j][0]);
                acc[j][1] = fmaf(p[2], wv.x, acc[j][1]);
                acc[j][1] = fmaf(p[3], wv.y, acc[j][1]);
                acc[j][1] = fmaf(p[4], wv.z, acc[j][1]);
                acc[j][1] = fmaf(p[5], wv.w, acc[j][1]);
            }
        }
    }
    float* ob = out + ((size_t)(n * COUT + cg * 8) * NPX) + px0;
#pragma unroll
    for (int j = 0; j < 8; ++j) {
        float2 v;
        v.x = acc[j][0];
        v.y = acc[j][1];
        if (relu) { v.x = fmaxf(v.x, 0.f); v.y = fmaxf(v.y, 0.f); }
        *(float2*)(ob + (size_t)j * NPX) = v;
    }
}

// ---------------------------------------------------------------------------
// L0: (5,256,192)->(8,128,96), +bias +ReLU. grid 1536, block 256.
// ci loop MUST stay unroll 1 (R6: full unroll -> VGPR 256 spill).
// ---------------------------------------------------------------------------
__global__ __launch_bounds__(256) void conv0(const float* __restrict__ in,
                                             const float* __restrict__ w,
                                             const float* __restrict__ bias,
                                             float* __restrict__ out)
{
    __shared__ float sW[5 * 8 * 16];
    __shared__ float sB[8];
    int t   = threadIdx.x;
    int n   = blockIdx.x / 24;
    int pxb = blockIdx.x % 24;
    for (int i = t; i < 640; i += 256) {
        int ci = i / 128;
        int r  = i % 128;
        int co = r / 16;
        int k  = r % 16;
        sW[i] = w[((size_t)co * 5 + ci) * 16 + k];
    }
    if (t < 8) sB[t] = bias[t];
    __syncthreads();

    int px0 = (pxb * 256 + t) * 2;
    int oh  = px0 / 96;
    int ow0 = px0 % 96;
    int ih0 = oh * 2 - 1;
    int iwq = ow0 * 2;

    float acc[8][2];
#pragma unroll
    for (int j = 0; j < 8; ++j) { acc[j][0] = sB[j]; acc[j][1] = sB[j]; }

    const float* ib = in + (size_t)n * 5 * 256 * 192;
#pragma unroll 1
    for (int ci = 0; ci < 5; ++ci) {
        const float* plane = ib + (size_t)ci * 256 * 192;
#pragma unroll
        for (int kh = 0; kh < 4; ++kh) {
            int ih = ih0 + kh;
            float p[6];
            if ((unsigned)ih < 256u) {
                const float* row = plane + (size_t)ih * 192;
                float4 q = *(const float4*)(row + iwq);
                p[1] = q.x; p[2] = q.y; p[3] = q.z; p[4] = q.w;
                p[0] = (iwq >= 1)      ? row[iwq - 1] : 0.f;
                p[5] = (iwq + 4 < 192) ? row[iwq + 4] : 0.f;
            } else {
#pragma unroll
                for (int k2 = 0; k2 < 6; ++k2) p[k2] = 0.f;
            }
#pragma unroll
            for (int j = 0; j < 8; ++j) {
                const float4 wv = *(const float4*)(sW + (ci * 8 + j) * 16 + kh * 4);
                acc[j][0] = fmaf(p[0], wv.x, acc[j][0]);
                acc[j][0] = fmaf(p[1], wv.y, acc[j][0]);
                acc[j][0] = fmaf(p[2], wv.z, acc[j][0]);
                acc[j][0] = fmaf(p[3], wv.w, acc[j][0]);
                acc[j][1] = fmaf(p[2], wv.x, acc[j][1]);
                acc[j][1] = fmaf(p[3], wv.y, acc[j][1]);
                acc[j][1] = fmaf(p[4], wv.z, acc[j][1]);
                acc[j][1] = fmaf(p[5], wv.w, acc[j][1]);
            }
        }
    }
    float* ob = out + (size_t)n * 8 * 12288 + px0;
#pragma unroll
    for (int j = 0; j < 8; ++j) {
        float2 v;
        v.x = fmaxf(acc[j][0], 0.f);
        v.y = fmaxf(acc[j][1], 0.f);
        *(float2*)(ob + (size_t)j * 12288) = v;
    }
}

// ---------------------------------------------------------------------------
// Instance norm for L2 output, writes TRANSPOSED [c][px][n] + relu.
// ---------------------------------------------------------------------------
__global__ __launch_bounds__(256) void inorm_wave_T768(const float* __restrict__ src,
                                                       float* __restrict__ dst_t)
{
    int gid  = blockIdx.x * blockDim.x + threadIdx.x;
    int wv   = gid >> 6;
    int lane = gid & 63;
    int n = wv >> 5;
    int c = wv & 31;
    const float* p = src + (size_t)wv * 768;
    float tv[12];
    float s1 = 0.f, s2 = 0.f;
#pragma unroll
    for (int k = 0; k < 12; ++k) {
        float v = p[lane + k * 64];
        tv[k] = v;
        s1 += v; s2 += v * v;
    }
    for (int m = 32; m >= 1; m >>= 1) {
        s1 += __shfl_xor(s1, m);
        s2 += __shfl_xor(s2, m);
    }
    float mean = s1 * (1.f / 768.f);
    float var  = s2 * (1.f / 768.f) - mean * mean;
    float r = rsqrtf(var + EPS);
#pragma unroll
    for (int k = 0; k < 12; ++k) {
        int i = lane + k * 64;
        float y = fmaxf((tv[k] - mean) * r, 0.f);
        dst_t[((size_t)c * 768 + i) * 64 + n] = y;
    }
}

// ---------------------------------------------------------------------------
// Single-pass instance norm: register-cached float4. HW = TPB*VPT*4. In place.
// ---------------------------------------------------------------------------
template<int TPB, int VPT>
__global__ void inorm_blockv(float* __restrict__ data, int relu)
{
    const int HW = TPB * VPT * 4;
    float4* p = (float4*)(data + (size_t)blockIdx.x * HW);
    float4 v[VPT];
    float s = 0.f, q = 0.f;
#pragma unroll
    for (int k = 0; k < VPT; ++k) {
        v[k] = p[threadIdx.x + k * TPB];
        s += v[k].x + v[k].y + v[k].z + v[k].w;
        q += v[k].x*v[k].x + v[k].y*v[k].y + v[k].z*v[k].z + v[k].w*v[k].w;
    }
    for (int m2 = 32; m2 >= 1; m2 >>= 1) {
        s += __shfl_xor(s, m2);
        q += __shfl_xor(q, m2);
    }
    __shared__ float ss[TPB / 64], sq[TPB / 64], sm[2];
    int wave = threadIdx.x >> 6, lane = threadIdx.x & 63;
    if (lane == 0) { ss[wave] = s; sq[wave] = q; }
    __syncthreads();
    if (threadIdx.x == 0) {
        float a = 0.f, b2 = 0.f;
#pragma unroll
        for (int k = 0; k < TPB / 64; ++k) { a += ss[k]; b2 += sq[k]; }
        float mm = a / (float)HW;
        float vv = b2 / (float)HW - mm * mm;
        sm[0] = mm; sm[1] = rsqrtf(vv + EPS);
    }
    __syncthreads();
    float m = sm[0], r = sm[1];
#pragma unroll
    for (int k = 0; k < VPT; ++k) {
        float4 y;
        y.x = (v[k].x - m) * r; y.y = (v[k].y - m) * r;
        y.z = (v[k].z - m) * r; y.w = (v[k].w - m) * r;
        if (relu) {
            y.x = fmaxf(y.x, 0.f); y.y = fmaxf(y.y, 0.f);
            y.z = fmaxf(y.z, 0.f); y.w = fmaxf(y.w, 0.f);
        }
        p[threadIdx.x + k * TPB] = y;
    }
}

// ---------------------------------------------------------------------------
// L3 conv (split, lane=n, transposed input [ci][768][n]). grid 512 x 256.
// Partials pbuf[(cic*4096 + n*64 + co)*192 + px]. No bias (cancels).
// ---------------------------------------------------------------------------
__global__ __launch_bounds__(256) void k_l3conv(const float* __restrict__ At2,
                                                const float* __restrict__ w3,
                                                float* __restrict__ pbuf)
{
    int t    = threadIdx.x;
    int lane = t & 63;
    int wid  = __builtin_amdgcn_readfirstlane(blockIdx.x * 4 + (t >> 6)); // 0..2047
    int cog = wid & 31;
    int cic = (wid >> 5) & 3;
    int oh  = wid >> 7;
    int cc  = cic * 8;
    int co0 = cog * 2;
    int ih0 = 2 * oh - 1;

    float acc[2][12];
#pragma unroll
    for (int j = 0; j < 2; ++j)
#pragma unroll
        for (int p = 0; p < 12; ++p) acc[j][p] = 0.f;

    const float* wb = w3 + ((size_t)co0 * 32 + cc) * 16;

#pragma unroll 1
    for (int ci = 0; ci < 8; ++ci) {
        const float* pl = At2 + (size_t)(cc + ci) * 768 * 64 + lane;
        float wr[2][16];
#pragma unroll
        for (int k = 0; k < 16; ++k) {
            wr[0][k] = wb[(0 * 32 + ci) * 16 + k];
            wr[1][k] = wb[(1 * 32 + ci) * 16 + k];
        }
#pragma unroll
        for (int kh = 0; kh < 4; ++kh) {
            int ih = ih0 + kh;
            float p[26];
            p[0] = 0.f; p[25] = 0.f;
            if ((unsigned)ih < 32u) {
#pragma unroll
                for (int c = 0; c < 24; ++c)
                    p[c + 1] = pl[(size_t)(ih * 24 + c) * 64];
            } else {
#pragma unroll
                for (int c = 0; c < 24; ++c) p[c + 1] = 0.f;
            }
#pragma unroll
            for (int ow = 0; ow < 12; ++ow) {
#pragma unroll
                for (int kw = 0; kw < 4; ++kw) {
                    float pv = p[2 * ow + kw];
                    acc[0][ow] = fmaf(pv, wr[0][kh * 4 + kw], acc[0][ow]);
                    acc[1][ow] = fmaf(pv, wr[1][kh * 4 + kw], acc[1][ow]);
                }
            }
        }
    }
    float* pb = pbuf + ((size_t)cic * 4096 + (size_t)lane * 64 + co0) * 192 + oh * 12;
#pragma unroll
    for (int j = 0; j < 2; ++j) {
        float4* o4 = (float4*)(pb + (size_t)j * 192);
        o4[0] = make_float4(acc[j][0], acc[j][1], acc[j][2],  acc[j][3]);
        o4[1] = make_float4(acc[j][4], acc[j][5], acc[j][6],  acc[j][7]);
        o4[2] = make_float4(acc[j][8], acc[j][9], acc[j][10], acc[j][11]);
    }
}

// L3 reduce: sum 4 splits + norm over 192 + relu, write transposed [co][192][n].
__global__ __launch_bounds__(256) void k_l3red(const float* __restrict__ pbuf,
                                               float* __restrict__ At)
{
    int gid  = blockIdx.x * blockDim.x + threadIdx.x;
    int wv   = gid >> 6;          // 0..4095 = n*64+co
    int lane = gid & 63;
    int n  = wv >> 6;
    int co = wv & 63;
    float tv[3];
#pragma unroll
    for (int k = 0; k < 3; ++k) {
        int i = lane + k * 64;
        float sum = 0.f;
#pragma unroll
        for (int s = 0; s < 4; ++s)
            sum += pbuf[((size_t)s * 4096 + wv) * 192 + i];
        tv[k] = sum;
    }
    float s1 = tv[0] + tv[1] + tv[2];
    float s2 = tv[0]*tv[0] + tv[1]*tv[1] + tv[2]*tv[2];
    for (int m = 32; m >= 1; m >>= 1) {
        s1 += __shfl_xor(s1, m);
        s2 += __shfl_xor(s2, m);
    }
    float mean = s1 * (1.f / 192.f);
    float var  = s2 * (1.f / 192.f) - mean * mean;
    float r = rsqrtf(var + EPS);
#pragma unroll
    for (int k = 0; k < 3; ++k) {
        int i = lane + k * 64;
        float y = fmaxf((tv[k] - mean) * r, 0.f);
        At[((size_t)co * 192 + i) * 64 + n] = y;
    }
}

// ---------------------------------------------------------------------------
// L4 FUSED conv+norm+relu: (64,16,12)->(128,8,6). Input transposed [ci][192][n].
// grid 128 (1 co/block), block 256: wave = (half, cichunk of 32), lane = n.
// LDS partial exchange + block norm; out [n][128][48].
// ---------------------------------------------------------------------------
__global__ __launch_bounds__(256) void l4_fused(const float* __restrict__ At,
                                                const float* __restrict__ w4,
                                                float* __restrict__ out)
{
    __shared__ float part[2][2][64][24];
    __shared__ float ex[2][64][2];
    int t = threadIdx.x, lane = t & 63, w = t >> 6;
    int half = w >> 1, cic = w & 1;
    int co = blockIdx.x;
    int oh0 = half * 4;

    float acc[24];
#pragma unroll
    for (int p = 0; p < 24; ++p) acc[p] = 0.f;

    const float* wp = w4 + ((size_t)co * 64 + cic * 32) * 16;

#pragma unroll 1
    for (int ci = 0; ci < 32; ++ci) {
        const float* pl = At + (size_t)(cic * 32 + ci) * 192 * 64 + lane;
        float wr[16];
#pragma unroll
        for (int k = 0; k < 16; ++k) wr[k] = wp[ci * 16 + k];
#pragma unroll
        for (int kh = 0; kh < 4; ++kh) {
            float p[4][12];
#pragma unroll
            for (int o = 0; o < 4; ++o) {
                int ih = 2 * (oh0 + o) - 1 + kh;
                if ((unsigned)ih < 16u) {
#pragma unroll
                    for (int c = 0; c < 12; ++c)
                        p[o][c] = pl[(size_t)(ih * 12 + c) * 64];
                } else {
#pragma unroll
                    for (int c = 0; c < 12; ++c) p[o][c] = 0.f;
                }
            }
#pragma unroll
            for (int o = 0; o < 4; ++o)
#pragma unroll
                for (int ow = 0; ow < 6; ++ow) {
#pragma unroll
                    for (int kw = 0; kw < 4; ++kw) {
                        int iw = 2 * ow - 1 + kw;
                        if (iw < 0 || iw >= 12) continue;
                        acc[o * 6 + ow] = fmaf(p[o][iw], wr[kh * 4 + kw], acc[o * 6 + ow]);
                    }
                }
        }
    }
#pragma unroll
    for (int p = 0; p < 24; ++p) part[half][cic][lane][p] = acc[p];
    __syncthreads();

    int h = w & 1;   // waves 0,2 -> h=0 (duplicate, harmless); 1,3 -> h=1
    float s[24];
    float s1 = 0.f, s2 = 0.f;
#pragma unroll
    for (int p = 0; p < 24; ++p) {
        s[p] = part[h][0][lane][p] + part[h][1][lane][p];
        s1 += s[p]; s2 += s[p] * s[p];
    }
    if (w < 2) { ex[h][lane][0] = s1; ex[h][lane][1] = s2; }
    __syncthreads();
    float S1 = ex[0][lane][0] + ex[1][lane][0];
    float S2 = ex[0][lane][1] + ex[1][lane][1];
    float mean = S1 * (1.f / 48.f);
    float var  = S2 * (1.f / 48.f) - mean * mean;
    float r = rsqrtf(var + EPS);
    if (w < 2) {
        float4* o4 = (float4*)(out + ((size_t)lane * 128 + co) * 48 + h * 24);
#pragma unroll
        for (int q = 0; q < 6; ++q) {
            float4 v;
            v.x = fmaxf((s[q * 4 + 0] - mean) * r, 0.f);
            v.y = fmaxf((s[q * 4 + 1] - mean) * r, 0.f);
            v.z = fmaxf((s[q * 4 + 2] - mean) * r, 0.f);
            v.w = fmaxf((s[q * 4 + 3] - mean) * r, 0.f);
            o4[q] = v;
        }
    }
}

// ---------------------------------------------------------------------------
// L5 FUSED: (128,8,6)->(256,4,3). grid 256 (1 co/block), waves = 4 ci-chunks
// of 32, lane = n. In [n][128][48]; out [n][256][12].
// ---------------------------------------------------------------------------
__global__ __launch_bounds__(256) void l5_fused(const float* __restrict__ in,
                                                const float* __restrict__ w5,
                                                float* __restrict__ out)
{
    __shared__ float part[4][64][12];
    int t = threadIdx.x, lane = t & 63, w = t >> 6;
    int co = blockIdx.x;

    float acc[12];
#pragma unroll
    for (int p = 0; p < 12; ++p) acc[p] = 0.f;

    const float* ip = in + ((size_t)lane * 128 + w * 32) * 48;
    const float* wp = w5 + ((size_t)co * 128 + w * 32) * 16;

#pragma unroll 1
    for (int ci = 0; ci < 32; ++ci) {
        float p[48];
        const float4* p4 = (const float4*)(ip + ci * 48);
#pragma unroll
        for (int q = 0; q < 12; ++q) {
            float4 a = p4[q];
            p[q * 4 + 0] = a.x; p[q * 4 + 1] = a.y;
            p[q * 4 + 2] = a.z; p[q * 4 + 3] = a.w;
        }
        float wr[16];
#pragma unroll
        for (int k = 0; k < 16; ++k) wr[k] = wp[ci * 16 + k];
#pragma unroll
        for (int oh = 0; oh < 4; ++oh)
#pragma unroll
            for (int ow = 0; ow < 3; ++ow) {
                int ih0 = 2 * oh - 1, iw0 = 2 * ow - 1;
#pragma unroll
                for (int kh = 0; kh < 4; ++kh) {
                    int ih = ih0 + kh;
                    if (ih < 0 || ih >= 8) continue;
#pragma unroll
                    for (int kw = 0; kw < 4; ++kw) {
                        int iw = iw0 + kw;
                        if (iw < 0 || iw >= 6) continue;
                        acc[oh * 3 + ow] = fmaf(p[ih * 6 + iw], wr[kh * 4 + kw], acc[oh * 3 + ow]);
                    }
                }
            }
    }
#pragma unroll
    for (int p = 0; p < 12; ++p) part[w][lane][p] = acc[p];
    __syncthreads();
    if (w == 0) {
        float s[12];
        float s1 = 0.f, s2 = 0.f;
#pragma unroll
        for (int p = 0; p < 12; ++p) {
            s[p] = part[0][lane][p] + part[1][lane][p] + part[2][lane][p] + part[3][lane][p];
            s1 += s[p]; s2 += s[p] * s[p];
        }
        float mean = s1 * (1.f / 12.f);
        float var  = s2 * (1.f / 12.f) - mean * mean;
        float r = rsqrtf(var + EPS);
        float y[12];
#pragma unroll
        for (int p = 0; p < 12; ++p) y[p] = fmaxf((s[p] - mean) * r, 0.f);
        float4* o4 = (float4*)(out + ((size_t)lane * 256 + co) * 12);
        o4[0] = make_float4(y[0], y[1], y[2],  y[3]);
        o4[1] = make_float4(y[4], y[5], y[6],  y[7]);
        o4[2] = make_float4(y[8], y[9], y[10], y[11]);
    }
}

// ---------------------------------------------------------------------------
// L6/L7 FUSED: (256,4,3)->(256,4,3), K=3,S=1,P=1. grid 256 (1 co/block),
// waves = 4 ci-chunks of 64, lane = n. In/out [n][256][12].
// ---------------------------------------------------------------------------
__global__ __launch_bounds__(256) void l67_fused(const float* __restrict__ in,
                                                 const float* __restrict__ wgt,
                                                 float* __restrict__ out)
{
    __shared__ float part[4][64][12];
    int t = threadIdx.x, lane = t & 63, w = t >> 6;
    int co = blockIdx.x;

    float acc[12];
#pragma unroll
    for (int p = 0; p < 12; ++p) acc[p] = 0.f;

    const float* ip = in + ((size_t)lane * 256 + w * 64) * 12;
    const float* wp = wgt + ((size_t)co * 256 + w * 64) * 9;

#pragma unroll 2
    for (int ci = 0; ci < 64; ++ci) {
        float p[12];
        const float4* p4 = (const float4*)(ip + ci * 12);
        float4 a0 = p4[0], a1 = p4[1], a2 = p4[2];
        p[0] = a0.x; p[1] = a0.y; p[2]  = a0.z; p[3]  = a0.w;
        p[4] = a1.x; p[5] = a1.y; p[6]  = a1.z; p[7]  = a1.w;
        p[8] = a2.x; p[9] = a2.y; p[10] = a2.z; p[11] = a2.w;
        float wr[9];
#pragma unroll
        for (int k = 0; k < 9; ++k) wr[k] = wp[ci * 9 + k];
#pragma unroll
        for (int oh = 0; oh < 4; ++oh)
#pragma unroll
            for (int ow = 0; ow < 3; ++ow)
#pragma unroll
                for (int kh = 0; kh < 3; ++kh) {
                    int ih = oh - 1 + kh;
                    if (ih < 0 || ih >= 4) continue;
#pragma unroll
                    for (int kw = 0; kw < 3; ++kw) {
                        int iw = ow - 1 + kw;
                        if (iw < 0 || iw >= 3) continue;
                        acc[oh * 3 + ow] = fmaf(p[ih * 3 + iw], wr[kh * 3 + kw], acc[oh * 3 + ow]);
                    }
                }
    }
#pragma unroll
    for (int p = 0; p < 12; ++p) part[w][lane][p] = acc[p];
    __syncthreads();
    if (w == 0) {
        float s[12];
        float s1 = 0.f, s2 = 0.f;
#pragma unroll
        for (int p = 0; p < 12; ++p) {
            s[p] = part[0][lane][p] + part[1][lane][p] + part[2][lane][p] + part[3][lane][p];
            s1 += s[p]; s2 += s[p] * s[p];
        }
        float mean = s1 * (1.f / 12.f);
        float var  = s2 * (1.f / 12.f) - mean * mean;
        float r = rsqrtf(var + EPS);
        float y[12];
#pragma unroll
        for (int p = 0; p < 12; ++p) y[p] = fmaxf((s[p] - mean) * r, 0.f);
        float4* o4 = (float4*)(out + ((size_t)lane * 256 + co) * 12);
        o4[0] = make_float4(y[0], y[1], y[2],  y[3]);
        o4[1] = make_float4(y[4], y[5], y[6],  y[7]);
        o4[2] = make_float4(y[8], y[9], y[10], y[11]);
    }
}

// ---------------------------------------------------------------------------
// pool + fc1 fused: block per n (64 x 128). maxpool to LDS, fc1 dot + relu.
// ---------------------------------------------------------------------------
__global__ __launch_bounds__(128) void pool_fc1(const float* __restrict__ in,
                                                const float* __restrict__ fc1_w,
                                                const float* __restrict__ fc1_b,
                                                float* __restrict__ fc1o)
{
    __shared__ float sPool[512];
    int t = threadIdx.x;
    int n = blockIdx.x;
    for (int f = t; f < 512; f += 128) {
        int c = f >> 1;
        int h = f & 1;
        const float* p = in + (((size_t)n * 256 + c) * 4 + h * 2) * 3;
        sPool[f] = fmaxf(fmaxf(p[0], p[1]), fmaxf(p[3], p[4]));
    }
    __syncthreads();
    const float* wr = fc1_w + t * 512;
    float acc = fc1_b[t];
#pragma unroll 4
    for (int f = 0; f < 512; ++f) acc = fmaf(sPool[f], wr[f], acc);
    fc1o[n * 128 + t] = fmaxf(acc, 0.f);
}

// ---------------------------------------------------------------------------
// fc2 + tanh + losses fused: 1 block x 256 (body validated in R12 coop run).
// ---------------------------------------------------------------------------
__global__ __launch_bounds__(256) void fc2_loss(const float* __restrict__ fc1o,
                                                const float* __restrict__ fc2_w,
                                                const float* __restrict__ fc2_b,
                                                float* __restrict__ out)
{
    __shared__ float sPts[3200];
    __shared__ float sAcc[4 * 64];
    int t = threadIdx.x;
    for (int idx = t; idx < 3200; idx += 256) {
        int n = idx / 50;
        int k = idx % 50;
        const float* xv = fc1o + n * 128;
        const float* wr = fc2_w + k * 128;
        float acc = fc2_b[k];
#pragma unroll 4
        for (int f = 0; f < 128; ++f) acc = fmaf(xv[f], wr[f], acc);
        float v = tanhf(acc);
        out[idx]  = v;
        sPts[idx] = v;
    }
    __syncthreads();
    if (t < 64) {
        int n = t;
        float rx = 0.f, ry = 0.f, cx = 0.f, cy = 0.f;
        const float* gp = sPts + n * 50;
        for (int r = 0; r < 5; ++r)
            for (int j = 0; j < 3; ++j)
                for (int d = 0; d < 2; ++d) {
                    float a0 = gp[(r * 5 + j) * 2 + d];
                    float a1 = gp[(r * 5 + j + 1) * 2 + d];
                    float a2 = gp[(r * 5 + j + 2) * 2 + d];
                    float d0 = (a1 - a0) * (a1 - a0);
                    float d1 = (a2 - a1) * (a2 - a1);
                    float tt = fmaxf(0.08f, fabsf(d1 - d0));
                    if (d == 0) rx += tt; else ry += tt;
                }
        for (int r = 0; r < 5; ++r)
            for (int j = 0; j < 3; ++j)
                for (int d = 0; d < 2; ++d) {
                    float a0 = gp[(j * 5 + r) * 2 + d];
                    float a1 = gp[((j + 1) * 5 + r) * 2 + d];
                    float a2 = gp[((j + 2) * 5 + r) * 2 + d];
                    float d0 = (a1 - a0) * (a1 - a0);
                    float d1 = (a2 - a1) * (a2 - a1);
                    float tt = fmaxf(0.08f, fabsf(d1 - d0));
                    if (d == 0) cx += tt; else cy += tt;
                }
        sAcc[0 * 64 + n] = rx; sAcc[1 * 64 + n] = ry;
        sAcc[2 * 64 + n] = cx; sAcc[3 * 64 + n] = cy;
    }
    __syncthreads();
    if (t == 0) {
        float s0 = 0.f, s1 = 0.f, s2 = 0.f, s3 = 0.f;
        for (int i = 0; i < 64; ++i) {
            s0 += sAcc[0 * 64 + i]; s1 += sAcc[1 * 64 + i];
            s2 += sAcc[2 * 64 + i]; s3 += sAcc[3 * 64 + i];
        }
        float inv = 1.0f / (64.0f * 15.0f);
        out[3200] = s0 * inv;
        out[3201] = s1 * inv;
        out[3202] = s2 * inv;
        out[3203] = s3 * inv;
        const float* gp = sPts;
        float rg = 0.f, cgs = 0.f;
        for (int r = 0; r < 5; ++r)
            for (int j = 0; j < 3; ++j) {
                float x0 = gp[(r * 5 + j) * 2],     y0 = gp[(r * 5 + j) * 2 + 1];
                float x1 = gp[(r * 5 + j + 1) * 2], y1 = gp[(r * 5 + j + 1) * 2 + 1];
                float x2 = gp[(r * 5 + j + 2) * 2], y2 = gp[(r * 5 + j + 2) * 2 + 1];
                rg += fabsf((y1 - y0) * (x1 - x2) - (y1 - y2) * (x1 - x0));
            }
        for (int r = 0; r < 5; ++r)
            for (int j = 0; j < 3; ++j) {
                float x0 = gp[(j * 5 + r) * 2],       y0 = gp[(j * 5 + r) * 2 + 1];
                float x1 = gp[((j + 1) * 5 + r) * 2], y1 = gp[((j + 1) * 5 + r) * 2 + 1];
                float x2 = gp[((j + 2) * 5 + r) * 2], y2 = gp[((j + 2) * 5 + r) * 2 + 1];
                cgs += fabsf((y1 - y0) * (x1 - x2) - (y1 - y2) * (x1 - x0));
            }
        out[3204] = fmaxf(rg, 0.02f);
        out[3205] = fmaxf(cgs, 0.02f);
    }
}

extern "C" void kernel_launch(void* const* d_in, const int* in_sizes, int n_in,
                              void* d_out, int out_size, void* d_ws, size_t ws_size,
                              hipStream_t stream)
{
    const float* x = (const float*)d_in[0];
    const float* w[8], *bia[8];
    for (int i = 0; i < 6; ++i) { w[i] = (const float*)d_in[1 + 2 * i]; bia[i] = (const float*)d_in[2 + 2 * i]; }
    w[6] = (const float*)d_in[13]; bia[6] = (const float*)d_in[14];
    w[7] = (const float*)d_in[15]; bia[7] = (const float*)d_in[16];
    const float* fc1_w = (const float*)d_in[17];
    const float* fc1_b = (const float*)d_in[18];
    const float* fc2_w = (const float*)d_in[19];
    const float* fc2_b = (const float*)d_in[20];
    float* out = (float*)d_out;

    // workspace (floats):
    float* A     = (float*)d_ws;       // [0 .. 6291456)
    float* Bf    = A + 6291456;        // [6291456 .. 9437184)
    float* At    = A;                  // L3 out transposed [64co][192][64n] = 786432
    float* At2   = A + 1572864;        // L2 normed transposed [32][768][64] = 1572864
    float* l4out = A + 1048576;        // [n][128][48] = 393216
    float* pbuf  = A + 3145728;        // L3 partials = 3145728
    float* fc1o  = A + 2097152;        // 8192
    float* l7out = Bf + 262144;        // [n][256][12] = 196608

    const int N = 64;

    // ---- L0: conv+bias+relu, then norm ----
    conv0<<<1536, 256, 0, stream>>>(x, w[0], bia[0], A);
    inorm_blockv<256, 12><<<N * 8, 256, 0, stream>>>(A, 0);

    // ---- L1 ----
    conv42V<8, 16, 128, 96, 256><<<768, 256, 0, stream>>>(A, w[1], bia[1], Bf, 0);
    inorm_blockv<256, 3><<<N * 16, 256, 0, stream>>>(Bf, 1);

    // ---- L2: raw out -> A[0..1572864), norm -> At2 (transposed) ----
    conv42V<16, 32, 64, 48, 192><<<512, 192, 0, stream>>>(Bf, w[2], bia[2], A, 0);
    inorm_wave_T768<<<512, 256, 0, stream>>>(A, At2);

    // ---- L3: split conv + reduce (transposed out) ----
    k_l3conv<<<512, 256, 0, stream>>>(At2, w[3], pbuf);
    k_l3red<<<1024, 256, 0, stream>>>(pbuf, At);

    // ---- L4-L7: fused conv+norm+relu per layer ----
    l4_fused<<<128, 256, 0, stream>>>(At, w[4], l4out);
    l5_fused<<<256, 256, 0, stream>>>(l4out, w[5], Bf);
    l67_fused<<<256, 256, 0, stream>>>(Bf, w[6], A);
    l67_fused<<<256, 256, 0, stream>>>(A, w[7], l7out);

    // ---- tail ----
    pool_fc1<<<64, 128, 0, stream>>>(l7out, fc1_w, fc1_b, fc1o);
    fc2_loss<<<1, 256, 0, stream>>>(fc1o, fc2_w, fc2_b, out);
}